// Round 1
// baseline (3707.127 us; speedup 1.0000x reference)
//
#include <hip/hip_runtime.h>
#include <cstdint>
#include <cstddef>

// Problem constants (Swin window attention)
#define B_WIN   2048
#define N_TOK   64
#define C_DIM   512
#define H_HEADS 16
#define D_HEAD  32
#define K_DIM   512
#define M_ROWS  (B_WIN * N_TOK)   // 131072

// ---------------------------------------------------------------------------
// Kernel 0: expand relative-position bias  bias_hn[h][i][j] = table[rel[i][j]][h]
// ---------------------------------------------------------------------------
__global__ void bias_expand_kernel(const float* __restrict__ bias_table,
                                   const int* __restrict__ rel_index,
                                   float* __restrict__ bias_hn) {
    int tid = blockIdx.x * 256 + threadIdx.x;   // 16 * 4096 = 65536 total
    int h  = tid >> 12;
    int ij = tid & 4095;
    bias_hn[tid] = bias_table[rel_index[ij] * H_HEADS + h];
}

// ---------------------------------------------------------------------------
// Kernel 1/3: fp32 GEMM, 128x128 tile, BK=16, 256 threads, 8x8 per thread.
//   mode 0: scatter output into qkv[3][B][H][N][D]
//   mode 1: add bias (proj_b) and store row-major [M, Ncols]
// ---------------------------------------------------------------------------
__global__ __launch_bounds__(256) void gemm128_kernel(
    const float* __restrict__ A,    // [M_ROWS, 512]
    const float* __restrict__ Bw,   // [512, Ncols]
    int Ncols,
    int mode,
    float* __restrict__ qkv_out,    // mode 0
    const float* __restrict__ bias, // mode 1
    float* __restrict__ out)        // mode 1
{
    __shared__ float As[16][128];   // As[k][m] (transposed store)
    __shared__ float Bs[16][128];   // Bs[k][n]

    const int t  = threadIdx.x;
    const int ty = t >> 4;          // 0..15
    const int tx = t & 15;          // 0..15
    const int m0 = blockIdx.y * 128;
    const int n0 = blockIdx.x * 128;

    float acc[8][8];
#pragma unroll
    for (int i = 0; i < 8; ++i)
#pragma unroll
        for (int j = 0; j < 8; ++j) acc[i][j] = 0.f;

    const int arow = t >> 1;        // 0..127
    const int acol = (t & 1) * 8;   // 0 or 8
    const int brow = t >> 4;        // 0..15
    const int bcol = (t & 15) * 8;  // 0..120

    for (int k0 = 0; k0 < K_DIM; k0 += 16) {
        float4 a0 = *reinterpret_cast<const float4*>(&A[(size_t)(m0 + arow) * K_DIM + k0 + acol]);
        float4 a1 = *reinterpret_cast<const float4*>(&A[(size_t)(m0 + arow) * K_DIM + k0 + acol + 4]);
        float4 b0 = *reinterpret_cast<const float4*>(&Bw[(size_t)(k0 + brow) * Ncols + n0 + bcol]);
        float4 b1 = *reinterpret_cast<const float4*>(&Bw[(size_t)(k0 + brow) * Ncols + n0 + bcol + 4]);

        As[acol + 0][arow] = a0.x; As[acol + 1][arow] = a0.y;
        As[acol + 2][arow] = a0.z; As[acol + 3][arow] = a0.w;
        As[acol + 4][arow] = a1.x; As[acol + 5][arow] = a1.y;
        As[acol + 6][arow] = a1.z; As[acol + 7][arow] = a1.w;
        *reinterpret_cast<float4*>(&Bs[brow][bcol])     = b0;
        *reinterpret_cast<float4*>(&Bs[brow][bcol + 4]) = b1;
        __syncthreads();

#pragma unroll
        for (int kk = 0; kk < 16; ++kk) {
            float4 af0 = *reinterpret_cast<const float4*>(&As[kk][ty * 8]);
            float4 af1 = *reinterpret_cast<const float4*>(&As[kk][ty * 8 + 4]);
            float4 bf0 = *reinterpret_cast<const float4*>(&Bs[kk][tx * 8]);
            float4 bf1 = *reinterpret_cast<const float4*>(&Bs[kk][tx * 8 + 4]);
            float a[8] = {af0.x, af0.y, af0.z, af0.w, af1.x, af1.y, af1.z, af1.w};
            float b[8] = {bf0.x, bf0.y, bf0.z, bf0.w, bf1.x, bf1.y, bf1.z, bf1.w};
#pragma unroll
            for (int i = 0; i < 8; ++i)
#pragma unroll
                for (int j = 0; j < 8; ++j)
                    acc[i][j] = fmaf(a[i], b[j], acc[i][j]);
        }
        __syncthreads();
    }

    const int colbase = n0 + tx * 8;
    if (mode == 0) {
        // column c -> (t, h, dd): t = c/512, h = (c/32)%16, dd = c%32.
        // colbase is a multiple of 8, so all 8 cols share t/h; dd contiguous.
        const int tsel = colbase >> 9;
        const int h    = (colbase >> 5) & 15;
        const int dd   = colbase & 31;
#pragma unroll
        for (int i = 0; i < 8; ++i) {
            const int row = m0 + ty * 8 + i;
            const int b   = row >> 6;
            const int n   = row & 63;
            size_t off = ((((size_t)tsel * B_WIN + b) * H_HEADS + h) * N_TOK + n) * D_HEAD + dd;
            float4 v0 = make_float4(acc[i][0], acc[i][1], acc[i][2], acc[i][3]);
            float4 v1 = make_float4(acc[i][4], acc[i][5], acc[i][6], acc[i][7]);
            *reinterpret_cast<float4*>(&qkv_out[off])     = v0;
            *reinterpret_cast<float4*>(&qkv_out[off + 4]) = v1;
        }
    } else {
        float4 pb0 = *reinterpret_cast<const float4*>(&bias[colbase]);
        float4 pb1 = *reinterpret_cast<const float4*>(&bias[colbase + 4]);
#pragma unroll
        for (int i = 0; i < 8; ++i) {
            const int row = m0 + ty * 8 + i;
            float4 v0 = make_float4(acc[i][0] + pb0.x, acc[i][1] + pb0.y,
                                    acc[i][2] + pb0.z, acc[i][3] + pb0.w);
            float4 v1 = make_float4(acc[i][4] + pb1.x, acc[i][5] + pb1.y,
                                    acc[i][6] + pb1.z, acc[i][7] + pb1.w);
            *reinterpret_cast<float4*>(&out[(size_t)row * Ncols + colbase])     = v0;
            *reinterpret_cast<float4*>(&out[(size_t)row * Ncols + colbase + 4]) = v1;
        }
    }
}

// ---------------------------------------------------------------------------
// Kernel 2: per-(b,h) window attention. 1 block = 1 (b,h), 256 threads.
//   S = q k^T * scale + bias; P = softmax(S); write P to attn_map; av = P v
// ---------------------------------------------------------------------------
__global__ __launch_bounds__(256) void attn_kernel(
    const float* __restrict__ qkv,      // [3][B][H][N][D]
    const float* __restrict__ bias_hn,  // [H][64][64]
    float* __restrict__ attn_map,       // [B][H][64][64]
    float* __restrict__ av)             // [B][N][H][D]
{
    __shared__ float qs[64][36];
    __shared__ float ks[64][36];
    __shared__ float vs[64][36];
    __shared__ float ps[64][65];

    const int bh = blockIdx.x;          // b*16 + h
    const int b  = bh >> 4;
    const int h  = bh & 15;
    const int t  = threadIdx.x;

    const size_t plane = (size_t)B_WIN * H_HEADS * N_TOK * D_HEAD;
    const size_t base  = (size_t)bh * (N_TOK * D_HEAD);
    const float* qg = qkv + base;
    const float* kg = qkv + plane + base;
    const float* vg = qkv + 2 * plane + base;

    // cooperative load: 2048 floats each, 8 per thread
    const int lr = t >> 2;              // 0..63
    const int lc = (t & 3) * 8;         // 0,8,16,24
    {
        float4 x0 = *reinterpret_cast<const float4*>(&qg[lr * 32 + lc]);
        float4 x1 = *reinterpret_cast<const float4*>(&qg[lr * 32 + lc + 4]);
        *reinterpret_cast<float4*>(&qs[lr][lc])     = x0;
        *reinterpret_cast<float4*>(&qs[lr][lc + 4]) = x1;
        float4 y0 = *reinterpret_cast<const float4*>(&kg[lr * 32 + lc]);
        float4 y1 = *reinterpret_cast<const float4*>(&kg[lr * 32 + lc + 4]);
        *reinterpret_cast<float4*>(&ks[lr][lc])     = y0;
        *reinterpret_cast<float4*>(&ks[lr][lc + 4]) = y1;
        float4 z0 = *reinterpret_cast<const float4*>(&vg[lr * 32 + lc]);
        float4 z1 = *reinterpret_cast<const float4*>(&vg[lr * 32 + lc + 4]);
        *reinterpret_cast<float4*>(&vs[lr][lc])     = z0;
        *reinterpret_cast<float4*>(&vs[lr][lc + 4]) = z1;
    }
    __syncthreads();

    const int r  = t >> 2;              // row 0..63
    const int c0 = (t & 3) * 16;        // col block

    float qr[32];
#pragma unroll
    for (int u = 0; u < 8; ++u) {
        float4 qf = *reinterpret_cast<const float4*>(&qs[r][u * 4]);
        qr[u * 4 + 0] = qf.x; qr[u * 4 + 1] = qf.y;
        qr[u * 4 + 2] = qf.z; qr[u * 4 + 3] = qf.w;
    }

    const float scale = 0.1767766952966369f;  // 32^-0.5
    float p[16];
#pragma unroll
    for (int j = 0; j < 16; ++j) {
        const int c = c0 + j;
        float s = 0.f;
#pragma unroll
        for (int kk = 0; kk < 32; kk += 4) {
            float4 kf = *reinterpret_cast<const float4*>(&ks[c][kk]);
            s = fmaf(qr[kk + 0], kf.x, s);
            s = fmaf(qr[kk + 1], kf.y, s);
            s = fmaf(qr[kk + 2], kf.z, s);
            s = fmaf(qr[kk + 3], kf.w, s);
        }
        p[j] = s * scale + bias_hn[(h << 12) + (r << 6) + c];
    }

    // softmax over row r, split across 4 threads (lanes r*4 .. r*4+3)
    float mx = p[0];
#pragma unroll
    for (int j = 1; j < 16; ++j) mx = fmaxf(mx, p[j]);
    mx = fmaxf(mx, __shfl_xor(mx, 1));
    mx = fmaxf(mx, __shfl_xor(mx, 2));
    float sum = 0.f;
#pragma unroll
    for (int j = 0; j < 16; ++j) { p[j] = __expf(p[j] - mx); sum += p[j]; }
    sum += __shfl_xor(sum, 1);
    sum += __shfl_xor(sum, 2);
    const float inv = 1.0f / sum;
#pragma unroll
    for (int j = 0; j < 16; ++j) p[j] *= inv;

#pragma unroll
    for (int j = 0; j < 16; ++j) ps[r][c0 + j] = p[j];

    {
        size_t ab = ((size_t)bh * 64 + r) * 64 + c0;
        *reinterpret_cast<float4*>(&attn_map[ab + 0])  = make_float4(p[0],  p[1],  p[2],  p[3]);
        *reinterpret_cast<float4*>(&attn_map[ab + 4])  = make_float4(p[4],  p[5],  p[6],  p[7]);
        *reinterpret_cast<float4*>(&attn_map[ab + 8])  = make_float4(p[8],  p[9],  p[10], p[11]);
        *reinterpret_cast<float4*>(&attn_map[ab + 12]) = make_float4(p[12], p[13], p[14], p[15]);
    }
    __syncthreads();

    // PV: av[r][dd0..dd0+7] = sum_j P[r][j] * v[j][dd]
    const int dd0 = (t & 3) * 8;
    float acc[8];
#pragma unroll
    for (int u = 0; u < 8; ++u) acc[u] = 0.f;
#pragma unroll 8
    for (int j = 0; j < 64; ++j) {
        const float pv = ps[r][j];
        float4 v0 = *reinterpret_cast<const float4*>(&vs[j][dd0]);
        float4 v1 = *reinterpret_cast<const float4*>(&vs[j][dd0 + 4]);
        acc[0] = fmaf(pv, v0.x, acc[0]);
        acc[1] = fmaf(pv, v0.y, acc[1]);
        acc[2] = fmaf(pv, v0.z, acc[2]);
        acc[3] = fmaf(pv, v0.w, acc[3]);
        acc[4] = fmaf(pv, v1.x, acc[4]);
        acc[5] = fmaf(pv, v1.y, acc[5]);
        acc[6] = fmaf(pv, v1.z, acc[6]);
        acc[7] = fmaf(pv, v1.w, acc[7]);
    }
    size_t o = (((size_t)b * 64 + r) * 16 + h) * 32 + dd0;
    *reinterpret_cast<float4*>(&av[o])     = make_float4(acc[0], acc[1], acc[2], acc[3]);
    *reinterpret_cast<float4*>(&av[o + 4]) = make_float4(acc[4], acc[5], acc[6], acc[7]);
}

// ---------------------------------------------------------------------------
extern "C" void kernel_launch(void* const* d_in, const int* in_sizes, int n_in,
                              void* d_out, int out_size, void* d_ws, size_t ws_size,
                              hipStream_t stream) {
    const float* x          = (const float*)d_in[0];
    const float* qkv_w      = (const float*)d_in[1];
    const float* proj_w     = (const float*)d_in[2];
    const float* proj_b     = (const float*)d_in[3];
    const float* bias_table = (const float*)d_in[4];
    const int*   rel_index  = (const int*)d_in[5];

    float* out      = (float*)d_out;                                   // [131072, 512]
    float* attn_map = (float*)d_out + (size_t)M_ROWS * C_DIM;          // [B][H][64][64]

    // workspace layout (floats): bias_hn | qkv | av   -> ~1.074 GB total
    float* ws      = (float*)d_ws;
    float* bias_hn = ws;                                               // 65536
    float* qkv     = ws + 65536;                                       // 3*B*H*N*D = 201326592
    float* av      = qkv + (size_t)3 * B_WIN * H_HEADS * N_TOK * D_HEAD; // 67108864

    bias_expand_kernel<<<256, 256, 0, stream>>>(bias_table, rel_index, bias_hn);
    gemm128_kernel<<<dim3(12, 1024), 256, 0, stream>>>(x, qkv_w, 3 * C_DIM, 0,
                                                       qkv, nullptr, nullptr);
    attn_kernel<<<B_WIN * H_HEADS, 256, 0, stream>>>(qkv, bias_hn, attn_map, av);
    gemm128_kernel<<<dim3(4, 1024), 256, 0, stream>>>(av, proj_w, C_DIM, 1,
                                                      nullptr, proj_b, out);
}

// Round 2
// 1731.114 us; speedup vs baseline: 2.1415x; 2.1415x over previous
//
#include <hip/hip_runtime.h>
#include <cstdint>
#include <cstddef>

// Problem constants (Swin window attention)
#define B_WIN   2048
#define N_TOK   64
#define C_DIM   512
#define H_HEADS 16
#define D_HEAD  32
#define K_DIM   512
#define M_ROWS  (B_WIN * N_TOK)   // 131072

typedef __bf16 bf16x8 __attribute__((ext_vector_type(8)));
typedef float  f32x4  __attribute__((ext_vector_type(4)));
typedef unsigned short u16x8 __attribute__((ext_vector_type(8)));

__device__ __forceinline__ unsigned short f2bf_rn(float f) {
    unsigned u = __float_as_uint(f);
    u += 0x7fffu + ((u >> 16) & 1u);
    return (unsigned short)(u >> 16);
}
__device__ __forceinline__ float bf2f(unsigned short h) {
    return __uint_as_float(((unsigned)h) << 16);
}
__device__ __forceinline__ void gload16(const void* g, void* l) {
    __builtin_amdgcn_global_load_lds(
        (const __attribute__((address_space(1))) void*)g,
        (__attribute__((address_space(3))) void*)l,
        16, 0, 0);
}

// ---------------------------------------------------------------------------
// Weight transpose + bf16 hi/lo split: w[K=512][N] -> wTh/wTl[N][512]
// ---------------------------------------------------------------------------
__global__ __launch_bounds__(256) void wsplit_kernel(
    const float* __restrict__ w,
    unsigned short* __restrict__ wTh,
    unsigned short* __restrict__ wTl,
    int Ncols)
{
    int idx = blockIdx.x * 256 + threadIdx.x;   // idx = n*512 + k
    int n = idx >> 9;
    int k = idx & 511;
    float v = w[(size_t)k * Ncols + n];
    unsigned short hi = f2bf_rn(v);
    wTh[idx] = hi;
    wTl[idx] = f2bf_rn(v - bf2f(hi));
}

// ---------------------------------------------------------------------------
// bf16x3-split MFMA GEMM: C = A * B   (A [M][512] fp32, B given as BT hi/lo
// [N][512] bf16).  128x128 tile, BK=32, 4 waves, mfma_f32_16x16x32_bf16.
//   mode 0: scatter into qkv[3][B][H][N][D]
//   mode 1: add bias, store row-major [M][Ncols]
// ---------------------------------------------------------------------------
__global__ __launch_bounds__(256) void gemm_split_kernel(
    const float* __restrict__ A,
    const unsigned short* __restrict__ BTh,
    const unsigned short* __restrict__ BTl,
    int mode,
    float* __restrict__ qkv_out,
    const float* __restrict__ bias,
    float* __restrict__ out,
    int Ncols)
{
    __shared__ __align__(16) unsigned short Ah[4096];  // [128 m][32 k]
    __shared__ __align__(16) unsigned short Al[4096];
    __shared__ __align__(16) unsigned short Bh[4096];  // [128 n][32 k]
    __shared__ __align__(16) unsigned short Bl[4096];

    const int t    = threadIdx.x;
    const int lane = t & 63;
    const int wave = t >> 6;
    const int lg   = lane >> 4;      // 0..3  (k-group)
    const int lr   = lane & 15;      // 0..15 (m / n within fragment)
    const int m0   = blockIdx.y * 128;
    const int n0   = blockIdx.x * 128;
    const int wrow = (wave >> 1) * 64;
    const int wcol = (wave & 1) * 64;

    f32x4 acc[4][4];
#pragma unroll
    for (int i = 0; i < 4; ++i)
#pragma unroll
        for (int j = 0; j < 4; ++j) acc[i][j] = (f32x4){0.f, 0.f, 0.f, 0.f};

    for (int k0 = 0; k0 < K_DIM; k0 += 32) {
        __syncthreads();   // previous tile fully consumed
        // ---- stage B: pre-split bf16, direct global->LDS (linear) ----
#pragma unroll
        for (int i = 0; i < 2; ++i) {
            const int c = i * 256 + t;                 // 16B chunk id
            const size_t g = (size_t)(n0 + (c >> 2)) * 512 + k0 + (c & 3) * 8;
            gload16(&BTh[g], &Bh[c * 8]);
            gload16(&BTl[g], &Bl[c * 8]);
        }
        // ---- stage A: fp32 -> hi/lo bf16 via registers ----
#pragma unroll
        for (int i = 0; i < 2; ++i) {
            const int c = i * 256 + t;
            const float* ap = &A[(size_t)(m0 + (c >> 2)) * 512 + k0 + (c & 3) * 8];
            float4 f0 = *reinterpret_cast<const float4*>(ap);
            float4 f1 = *reinterpret_cast<const float4*>(ap + 4);
            float fv[8] = {f0.x, f0.y, f0.z, f0.w, f1.x, f1.y, f1.z, f1.w};
            u16x8 hi, lo;
#pragma unroll
            for (int j = 0; j < 8; ++j) {
                unsigned short h = f2bf_rn(fv[j]);
                hi[j] = h;
                lo[j] = f2bf_rn(fv[j] - bf2f(h));
            }
            *reinterpret_cast<u16x8*>(&Ah[c * 8]) = hi;
            *reinterpret_cast<u16x8*>(&Al[c * 8]) = lo;
        }
        __syncthreads();   // waits vmcnt(0)+lgkmcnt(0): DMA + ds_writes done

        // ---- fragments + MFMA ----
        bf16x8 ah[4], al[4];
#pragma unroll
        for (int mi = 0; mi < 4; ++mi) {
            const int off = (wrow + mi * 16 + lr) * 32 + lg * 8;
            ah[mi] = *reinterpret_cast<const bf16x8*>(&Ah[off]);
            al[mi] = *reinterpret_cast<const bf16x8*>(&Al[off]);
        }
#pragma unroll
        for (int ni = 0; ni < 4; ++ni) {
            const int off = (wcol + ni * 16 + lr) * 32 + lg * 8;
            bf16x8 bh = *reinterpret_cast<const bf16x8*>(&Bh[off]);
            bf16x8 bl = *reinterpret_cast<const bf16x8*>(&Bl[off]);
#pragma unroll
            for (int mi = 0; mi < 4; ++mi) {
                acc[mi][ni] = __builtin_amdgcn_mfma_f32_16x16x32_bf16(ah[mi], bh, acc[mi][ni], 0, 0, 0);
                acc[mi][ni] = __builtin_amdgcn_mfma_f32_16x16x32_bf16(ah[mi], bl, acc[mi][ni], 0, 0, 0);
                acc[mi][ni] = __builtin_amdgcn_mfma_f32_16x16x32_bf16(al[mi], bh, acc[mi][ni], 0, 0, 0);
            }
        }
    }

    // ---- epilogue: C/D layout col=lane&15, row=(lane>>4)*4+reg ----
    if (mode == 0) {
#pragma unroll
        for (int mi = 0; mi < 4; ++mi)
#pragma unroll
            for (int ni = 0; ni < 4; ++ni) {
                const int col  = n0 + wcol + ni * 16 + lr;
                const int tsel = col >> 9;
                const int h    = (col >> 5) & 15;
                const int dd   = col & 31;
#pragma unroll
                for (int reg = 0; reg < 4; ++reg) {
                    const int row = m0 + wrow + mi * 16 + lg * 4 + reg;
                    const int b = row >> 6, n = row & 63;
                    qkv_out[((((size_t)tsel * B_WIN + b) * H_HEADS + h) * N_TOK + n) * D_HEAD + dd]
                        = acc[mi][ni][reg];
                }
            }
    } else {
#pragma unroll
        for (int mi = 0; mi < 4; ++mi)
#pragma unroll
            for (int ni = 0; ni < 4; ++ni) {
                const int col = n0 + wcol + ni * 16 + lr;
                const float pb = bias[col];
#pragma unroll
                for (int reg = 0; reg < 4; ++reg) {
                    const int row = m0 + wrow + mi * 16 + lg * 4 + reg;
                    out[(size_t)row * Ncols + col] = acc[mi][ni][reg] + pb;
                }
            }
    }
}

// ---------------------------------------------------------------------------
// Kernel 2: per-(b,h) window attention (unchanged fp32 path; bias gathered
// directly from table via rel_index -> L1-resident, no expanded buffer)
// ---------------------------------------------------------------------------
__global__ __launch_bounds__(256) void attn_kernel(
    const float* __restrict__ qkv,        // [3][B][H][N][D]
    const float* __restrict__ bias_table, // [(2ws-1)^2][H]
    const int*   __restrict__ rel_index,  // [64][64]
    float* __restrict__ attn_map,         // [B][H][64][64]
    float* __restrict__ av)               // [B][N][H][D] = [M][512]
{
    __shared__ float qs[64][36];
    __shared__ float ks[64][36];
    __shared__ float vs[64][36];
    __shared__ float ps[64][65];

    const int bh = blockIdx.x;
    const int b  = bh >> 4;
    const int h  = bh & 15;
    const int t  = threadIdx.x;

    const size_t plane = (size_t)B_WIN * H_HEADS * N_TOK * D_HEAD;
    const size_t base  = (size_t)bh * (N_TOK * D_HEAD);
    const float* qg = qkv + base;
    const float* kg = qkv + plane + base;
    const float* vg = qkv + 2 * plane + base;

    const int lr = t >> 2;
    const int lc = (t & 3) * 8;
    {
        float4 x0 = *reinterpret_cast<const float4*>(&qg[lr * 32 + lc]);
        float4 x1 = *reinterpret_cast<const float4*>(&qg[lr * 32 + lc + 4]);
        *reinterpret_cast<float4*>(&qs[lr][lc])     = x0;
        *reinterpret_cast<float4*>(&qs[lr][lc + 4]) = x1;
        float4 y0 = *reinterpret_cast<const float4*>(&kg[lr * 32 + lc]);
        float4 y1 = *reinterpret_cast<const float4*>(&kg[lr * 32 + lc + 4]);
        *reinterpret_cast<float4*>(&ks[lr][lc])     = y0;
        *reinterpret_cast<float4*>(&ks[lr][lc + 4]) = y1;
        float4 z0 = *reinterpret_cast<const float4*>(&vg[lr * 32 + lc]);
        float4 z1 = *reinterpret_cast<const float4*>(&vg[lr * 32 + lc + 4]);
        *reinterpret_cast<float4*>(&vs[lr][lc])     = z0;
        *reinterpret_cast<float4*>(&vs[lr][lc + 4]) = z1;
    }
    __syncthreads();

    const int r  = t >> 2;
    const int c0 = (t & 3) * 16;

    float qr[32];
#pragma unroll
    for (int u = 0; u < 8; ++u) {
        float4 qf = *reinterpret_cast<const float4*>(&qs[r][u * 4]);
        qr[u * 4 + 0] = qf.x; qr[u * 4 + 1] = qf.y;
        qr[u * 4 + 2] = qf.z; qr[u * 4 + 3] = qf.w;
    }

    const float scale = 0.1767766952966369f;  // 32^-0.5
    float p[16];
#pragma unroll
    for (int j = 0; j < 16; ++j) {
        const int c = c0 + j;
        float s = 0.f;
#pragma unroll
        for (int kk = 0; kk < 32; kk += 4) {
            float4 kf = *reinterpret_cast<const float4*>(&ks[c][kk]);
            s = fmaf(qr[kk + 0], kf.x, s);
            s = fmaf(qr[kk + 1], kf.y, s);
            s = fmaf(qr[kk + 2], kf.z, s);
            s = fmaf(qr[kk + 3], kf.w, s);
        }
        p[j] = fmaf(s, scale, bias_table[rel_index[(r << 6) + c] * H_HEADS + h]);
    }

    float mx = p[0];
#pragma unroll
    for (int j = 1; j < 16; ++j) mx = fmaxf(mx, p[j]);
    mx = fmaxf(mx, __shfl_xor(mx, 1));
    mx = fmaxf(mx, __shfl_xor(mx, 2));
    float sum = 0.f;
#pragma unroll
    for (int j = 0; j < 16; ++j) { p[j] = __expf(p[j] - mx); sum += p[j]; }
    sum += __shfl_xor(sum, 1);
    sum += __shfl_xor(sum, 2);
    const float inv = 1.0f / sum;
#pragma unroll
    for (int j = 0; j < 16; ++j) p[j] *= inv;

#pragma unroll
    for (int j = 0; j < 16; ++j) ps[r][c0 + j] = p[j];

    {
        size_t ab = ((size_t)bh * 64 + r) * 64 + c0;
        *reinterpret_cast<float4*>(&attn_map[ab + 0])  = make_float4(p[0],  p[1],  p[2],  p[3]);
        *reinterpret_cast<float4*>(&attn_map[ab + 4])  = make_float4(p[4],  p[5],  p[6],  p[7]);
        *reinterpret_cast<float4*>(&attn_map[ab + 8])  = make_float4(p[8],  p[9],  p[10], p[11]);
        *reinterpret_cast<float4*>(&attn_map[ab + 12]) = make_float4(p[12], p[13], p[14], p[15]);
    }
    __syncthreads();

    const int dd0 = (t & 3) * 8;
    float acc[8];
#pragma unroll
    for (int u = 0; u < 8; ++u) acc[u] = 0.f;
#pragma unroll 8
    for (int j = 0; j < 64; ++j) {
        const float pv = ps[r][j];
        float4 v0 = *reinterpret_cast<const float4*>(&vs[j][dd0]);
        float4 v1 = *reinterpret_cast<const float4*>(&vs[j][dd0 + 4]);
        acc[0] = fmaf(pv, v0.x, acc[0]);
        acc[1] = fmaf(pv, v0.y, acc[1]);
        acc[2] = fmaf(pv, v0.z, acc[2]);
        acc[3] = fmaf(pv, v0.w, acc[3]);
        acc[4] = fmaf(pv, v1.x, acc[4]);
        acc[5] = fmaf(pv, v1.y, acc[5]);
        acc[6] = fmaf(pv, v1.z, acc[6]);
        acc[7] = fmaf(pv, v1.w, acc[7]);
    }
    size_t o = (((size_t)b * 64 + r) * 16 + h) * 32 + dd0;
    *reinterpret_cast<float4*>(&av[o])     = make_float4(acc[0], acc[1], acc[2], acc[3]);
    *reinterpret_cast<float4*>(&av[o + 4]) = make_float4(acc[4], acc[5], acc[6], acc[7]);
}

// ---------------------------------------------------------------------------
extern "C" void kernel_launch(void* const* d_in, const int* in_sizes, int n_in,
                              void* d_out, int out_size, void* d_ws, size_t ws_size,
                              hipStream_t stream) {
    const float* x          = (const float*)d_in[0];
    const float* qkv_w      = (const float*)d_in[1];
    const float* proj_w     = (const float*)d_in[2];
    const float* proj_b     = (const float*)d_in[3];
    const float* bias_table = (const float*)d_in[4];
    const int*   rel_index  = (const int*)d_in[5];

    float* out      = (float*)d_out;                           // [131072][512]
    float* attn_map = (float*)d_out + (size_t)M_ROWS * C_DIM;  // [B][H][64][64]

    // workspace: qkv (805,306,368 B) | av (268,435,456 B)  == exactly 1 GiB.
    // Weight split buffers live in temporally-dead regions:
    //   qkv_wT  -> head of av region  (dead until attention writes av)
    //   proj_wT -> head of qkv region (dead after attention reads qkv)
    float* qkv = (float*)d_ws;
    float* av  = qkv + (size_t)3 * B_WIN * H_HEADS * N_TOK * D_HEAD;

    unsigned short* qwTh = (unsigned short*)av;
    unsigned short* qwTl = qwTh + (size_t)1536 * 512;
    unsigned short* pwTh = (unsigned short*)qkv;
    unsigned short* pwTl = pwTh + (size_t)512 * 512;

    wsplit_kernel<<<3072, 256, 0, stream>>>(qkv_w, qwTh, qwTl, 1536);
    gemm_split_kernel<<<dim3(12, 1024), 256, 0, stream>>>(
        x, qwTh, qwTl, 0, qkv, nullptr, nullptr, 1536);
    attn_kernel<<<B_WIN * H_HEADS, 256, 0, stream>>>(
        qkv, bias_table, rel_index, attn_map, av);
    wsplit_kernel<<<1024, 256, 0, stream>>>(proj_w, pwTh, pwTl, 512);
    gemm_split_kernel<<<dim3(4, 1024), 256, 0, stream>>>(
        av, pwTh, pwTl, 1, nullptr, proj_b, out, 512);
}